// Round 2
// baseline (628.755 us; speedup 1.0000x reference)
//
#include <hip/hip_runtime.h>
#include <math.h>

#define D_MODEL 4096
#define N_EXP   64
#define N_ROWS  16384          // 4 * 4096
#define LN_EPS  1e-5f
#define TM      64             // rows per block
#define KC      64             // k-chunk
#define NCH     (D_MODEL / KC) // 64 chunks
#define NBLK    (N_ROWS / TM)  // 256 blocks

// ------------------------------------------------------------------
// ws layout (floats):
//   [0, 262144)        gWT[kg][e][4]: gWT[(kg*64+e)*4 + j] = W[e][4kg+j]*gamma[4kg+j]
//   [262144, 262208)   G[e] = sum_d gamma[d]*W[e][d]
//   [262208, 262272)   C[e] = sum_d beta[d]*W[e][d] + b[e]
//   [262272, 278656)   partials[NBLK][64] per-block mean_w sums
// ------------------------------------------------------------------

typedef __attribute__((address_space(3))) void        lds_vp;
typedef const __attribute__((address_space(1))) void  g_vp;

__device__ __forceinline__ void gld_lds16(const float* g, float* l) {
  // LDS dest = wave-uniform base + lane*16 (HW rule); pass the uniform base.
  __builtin_amdgcn_global_load_lds((g_vp*)g, (lds_vp*)l, 16, 0, 0);
}

// --- prep 1: gWT transpose (coalesced writes), grid 256 x 256 ---
__global__ __launch_bounds__(256) void prep_transpose(
    const float* __restrict__ W, const float* __restrict__ gamma,
    float* __restrict__ gWT)
{
  const int b = blockIdx.x, t = threadIdx.x;
  const int e = t & 63, kgl = t >> 6;        // 4 k-groups per block
  const int kg = b * 4 + kgl;                // global k-group (0..1023)
  const int d0 = kg * 4;
  const float4 wv = *(const float4*)(W + (size_t)e * D_MODEL + d0);
  const float4 gv = *(const float4*)(gamma + d0);
  float4 p;
  p.x = wv.x * gv.x; p.y = wv.y * gv.y; p.z = wv.z * gv.z; p.w = wv.w * gv.w;
  *(float4*)(gWT + ((size_t)kg * 64 + e) * 4) = p;
}

// --- prep 2: G[e], C[e], grid 64 x 256 ---
__global__ __launch_bounds__(256) void prep_gc(
    const float* __restrict__ W, const float* __restrict__ gamma,
    const float* __restrict__ beta, const float* __restrict__ bias,
    float* __restrict__ G, float* __restrict__ C)
{
  const int e = blockIdx.x, t = threadIdx.x;
  float sg = 0.f, sb = 0.f;
#pragma unroll
  for (int i = 0; i < 4; ++i) {
    const int d = (i * 256 + t) * 4;
    const float4 wv = *(const float4*)(W + (size_t)e * D_MODEL + d);
    const float4 gv = *(const float4*)(gamma + d);
    const float4 bv = *(const float4*)(beta + d);
    sg += wv.x * gv.x + wv.y * gv.y + wv.z * gv.z + wv.w * gv.w;
    sb += wv.x * bv.x + wv.y * bv.y + wv.z * bv.z + wv.w * bv.w;
  }
#pragma unroll
  for (int o = 32; o > 0; o >>= 1) {
    sg += __shfl_xor(sg, o, 64);
    sb += __shfl_xor(sb, o, 64);
  }
  __shared__ float rg_[4], rb_[4];
  const int wid = t >> 6, ln = t & 63;
  if (ln == 0) { rg_[wid] = sg; rb_[wid] = sb; }
  __syncthreads();
  if (t == 0) {
    G[e] = rg_[0] + rg_[1] + rg_[2] + rg_[3];
    C[e] = rb_[0] + rb_[1] + rb_[2] + rb_[3] + bias[e];
  }
}

// --- staging: x tile (row-major 64x64) + w tile ([kg][e][4]) via global_load_lds ---
__device__ __forceinline__ void stage_tiles(
    const float* __restrict__ x, const float* __restrict__ gWT,
    float* xbuf, float* wbuf, int w, int lane, size_t row_base, int kb)
{
#pragma unroll
  for (int i = 0; i < 4; ++i) {
    // x: rows w*16+i*4 .. +3, k slice [kb, kb+64); lane L -> row +(L>>4), k-off (L&15)*4
    const float* gx = x + (row_base + (size_t)(w * 16 + i * 4 + (lane >> 4))) * D_MODEL
                        + kb + (lane & 15) * 4;
    gld_lds16(gx, xbuf + (w * 16 + i * 4) * 64);
    // w: k-group kgl = w*4+i, lane = expert
    const float* gw = gWT + ((size_t)(kb / 4 + w * 4 + i) * 64 + lane) * 4;
    gld_lds16(gw, wbuf + (w * 4 + i) * 256);
  }
}

__global__ __launch_bounds__(256) void router_main(
    const float* __restrict__ x, const float* __restrict__ gWT,
    const float* __restrict__ G, const float* __restrict__ C,
    float* __restrict__ out_sw, float* __restrict__ out_idx,
    float* __restrict__ out_partials, int k)
{
  __shared__ float xb[2][TM * KC];     // 2 x 16 KB, row-major [row][k], no pad
  __shared__ float wb[2][KC * N_EXP];  // 2 x 16 KB, [kg][e][4]
  __shared__ float mu_s[TM], rs_s[TM];

  const int t    = threadIdx.x;
  const int w    = t >> 6;       // wave id (0..3): owns rows w*16..+15
  const int lane = t & 63;       // = expert index in GEMM/epilogue
  const int blk  = blockIdx.x;
  const size_t row_base = (size_t)blk * TM;

  float acc[16];
#pragma unroll
  for (int r = 0; r < 16; ++r) acc[r] = 0.f;
  float Sp[4] = {0.f, 0.f, 0.f, 0.f}, Qp[4] = {0.f, 0.f, 0.f, 0.f};

  stage_tiles(x, gWT, xb[0], wb[0], w, lane, row_base, 0);

  for (int c = 0; c < NCH; ++c) {
    // barrier drains this wave's vmcnt -> tile c resident; prefetch c+1 is
    // issued AFTER the barrier so the drain never waits on it.
    __syncthreads();
    if (c + 1 < NCH)
      stage_tiles(x, gWT, xb[(c + 1) & 1], wb[(c + 1) & 1], w, lane, row_base, (c + 1) * KC);

    const float* xt = xb[c & 1];
    const float* wt = wb[c & 1];
#pragma unroll
    for (int kg = 0; kg < 16; ++kg) {
      const float4 w4 = *(const float4*)(wt + kg * 256 + lane * 4);  // conflict-free
#pragma unroll
      for (int r = 0; r < 16; ++r) {
        const float4 x4 = *(const float4*)(xt + (w * 16 + r) * 64 + kg * 4);  // broadcast
        acc[r] = fmaf(x4.x, w4.x, fmaf(x4.y, w4.y, fmaf(x4.z, w4.z, fmaf(x4.w, w4.w, acc[r]))));
      }
    }
    // LN stats sweep of the staged x tile (conflict-free b128: lanes consecutive 16B)
#pragma unroll
    for (int i = 0; i < 4; ++i) {
      const float4 v = *(const float4*)(xt + (w * 16 + i * 4 + (lane >> 4)) * 64 + (lane & 15) * 4);
      Sp[i] += v.x + v.y + v.z + v.w;
      Qp[i] = fmaf(v.x, v.x, Qp[i]);
      Qp[i] = fmaf(v.y, v.y, Qp[i]);
      Qp[i] = fmaf(v.z, v.z, Qp[i]);
      Qp[i] = fmaf(v.w, v.w, Qp[i]);
    }
  }

  // reduce S/Q across the 16 lanes sharing a row (xor bits 0..3 keep lane>>4 fixed)
#pragma unroll
  for (int i = 0; i < 4; ++i) {
#pragma unroll
    for (int o = 1; o < 16; o <<= 1) {
      Sp[i] += __shfl_xor(Sp[i], o, 64);
      Qp[i] += __shfl_xor(Qp[i], o, 64);
    }
  }
  if ((lane & 15) == 0) {
#pragma unroll
    for (int i = 0; i < 4; ++i) {
      const int r   = w * 16 + i * 4 + (lane >> 4);
      const float mu  = Sp[i] * (1.f / D_MODEL);
      const float var = Qp[i] * (1.f / D_MODEL) - mu * mu;
      mu_s[r] = mu;
      rs_s[r] = rsqrtf(var + LN_EPS);
    }
  }
  __syncthreads();

  // epilogue: lane = expert; acc[r] is already logit-shaped (no LDS round-trip)
  const float Gv = G[lane];
  const float Cv = C[lane];
  float mw = 0.f;
  for (int r = 0; r < 16; ++r) {
    const int row = w * 16 + r;
    const float l = rs_s[row] * (acc[r] - mu_s[row] * Gv) + Cv;
    float m = l;
#pragma unroll
    for (int o = 32; o > 0; o >>= 1) m = fmaxf(m, __shfl_xor(m, o, 64));
    const float p = __expf(l - m);
    float s = p;
#pragma unroll
    for (int o = 32; o > 0; o >>= 1) s += __shfl_xor(s, o, 64);
    const float wv = p / s;
    mw += wv;

    float rem = wv, denom = 0.f, myval = 0.f;
    for (int j = 0; j < k; ++j) {
      float mx = rem;
#pragma unroll
      for (int o = 32; o > 0; o >>= 1) mx = fmaxf(mx, __shfl_xor(mx, o, 64));
      const unsigned long long ball = __ballot(rem == mx);
      const int ie = __ffsll((long long)ball) - 1;   // lowest index on ties (jax semantics)
      denom += mx;
      if (lane == ie) { myval = wv; rem = -1.f; }
      if (lane == j) out_idx[(row_base + row) * k + j] = (float)ie;
    }
    out_sw[(row_base + row) * N_EXP + lane] = myval / (denom + 1e-8f);
  }

  // per-block mean_w partial (deterministic)
  __syncthreads();
  xb[0][t] = mw;
  __syncthreads();
  if (t < 64)
    out_partials[blk * 64 + t] = xb[0][t] + xb[0][64 + t] + xb[0][128 + t] + xb[0][192 + t];
}

__global__ __launch_bounds__(256) void loss_kernel(
    const float* __restrict__ partials, float* __restrict__ out_loss)
{
  const int t = threadIdx.x, e = t & 63, q = t >> 6;
  float s = 0.f;
#pragma unroll 8
  for (int b = 0; b < 64; ++b) s += partials[(q * 64 + b) * 64 + e];
  __shared__ float sh[256];
  sh[t] = s;
  __syncthreads();
  if (t < 64) {
    const float m = (sh[t] + sh[64 + t] + sh[128 + t] + sh[192 + t]) * (1.f / N_ROWS);
    float v = -m * logf(m + 1e-8f);
#pragma unroll
    for (int o = 32; o > 0; o >>= 1) v += __shfl_xor(v, o, 64);
    if (t == 0) out_loss[0] = v;
  }
}

extern "C" void kernel_launch(void* const* d_in, const int* in_sizes, int n_in,
                              void* d_out, int out_size, void* d_ws, size_t ws_size,
                              hipStream_t stream)
{
  const float* x     = (const float*)d_in[0];
  const float* gamma = (const float*)d_in[1];
  const float* beta  = (const float*)d_in[2];
  const float* W     = (const float*)d_in[3];
  const float* bias  = (const float*)d_in[4];

  float* ws       = (float*)d_ws;
  float* gWT      = ws;
  float* G        = ws + 262144;
  float* C        = ws + 262208;
  float* partials = ws + 262272;

  int k = (out_size - N_ROWS * N_EXP - 1) / N_ROWS;
  if (k < 1) k = 1;
  if (k > 8) k = 8;

  float* out      = (float*)d_out;
  float* out_sw   = out;
  float* out_idx  = out + (size_t)N_ROWS * N_EXP;
  float* out_loss = out + (size_t)N_ROWS * N_EXP + (size_t)N_ROWS * k;

  hipLaunchKernelGGL(prep_transpose, dim3(256), dim3(256), 0, stream, W, gamma, gWT);
  hipLaunchKernelGGL(prep_gc, dim3(N_EXP), dim3(256), 0, stream, W, gamma, beta, bias, G, C);
  hipLaunchKernelGGL(router_main, dim3(NBLK), dim3(256), 0, stream,
                     x, gWT, G, C, out_sw, out_idx, partials, k);
  hipLaunchKernelGGL(loss_kernel, dim3(1), dim3(256), 0, stream, partials, out_loss);
}